// Round 1
// baseline (304.539 us; speedup 1.0000x reference)
//
#include <hip/hip_runtime.h>
#include <math.h>

// Problem dims
#define BB  8
#define SS  512
#define EE  128
#define HH  16
#define DKK 8
#define LL  4
#define FF  512
#define NQQ 4
#define CC  10

// ---------------------------------------------------------------------------
// Repack weights for coalesced per-lane float4 loads in fused_kernel.
// WoP[((l*32+kq)*128+e)*4+c] = Wo[l][e][kq*4+c]      (L*E*E  = 65536)
// W2P[((l*128+jq)*128+e)*4+c] = W2[l][e][jq*4+c]     (L*E*F  = 262144)
// ---------------------------------------------------------------------------
__global__ __launch_bounds__(256) void transpose_kernel(
    const float* __restrict__ Wo, const float* __restrict__ W2,
    float* __restrict__ WoP, float* __restrict__ W2P)
{
    int i = blockIdx.x * 256 + threadIdx.x;
    if (i < LL * EE * EE) {
        int c = i & 3, e = (i >> 2) & 127, kq = (i >> 9) & 31, l = i >> 14;
        WoP[i] = Wo[(l * EE + e) * EE + kq * 4 + c];
    }
    if (i < LL * EE * FF) {
        int c = i & 3, e = (i >> 2) & 127, jq = (i >> 9) & 127, l = i >> 16;
        W2P[i] = W2[(l * EE + e) * FF + jq * 4 + c];
    }
}

// ---------------------------------------------------------------------------
// h[b,s,e] = emb[tokens[b,s], e] + PE(s, e)
// ---------------------------------------------------------------------------
__global__ __launch_bounds__(256) void embed_kernel(
    const int* __restrict__ tokens, const float* __restrict__ emb,
    float* __restrict__ h)
{
    int i  = blockIdx.x * 256 + threadIdx.x;   // over B*S*E
    int e  = i & 127;
    int bs = i >> 7;
    int s  = bs & 511;
    int tok = tokens[bs];
    int half = e >> 1;
    // div = exp(-(2*half) * ln(10000)/128)
    float ang = (float)s * expf(-0.07195578415606394f * (float)(2 * half));
    float pe  = (e & 1) ? cosf(ang) : sinf(ang);
    h[i] = emb[tok * EE + e] + pe;
}

// ---------------------------------------------------------------------------
// enc[bh, s, d] = ring_measure(cos(h[b,s,hh*8+d] + theta[d]))
// ---------------------------------------------------------------------------
__global__ __launch_bounds__(256) void enc_kernel(
    const float* __restrict__ h, const float* __restrict__ theta,
    float* __restrict__ enc)
{
    int i  = blockIdx.x * 256 + threadIdx.x;   // over B*H*S
    int s  = i & 511;
    int bh = i >> 9;
    int hh = bh & 15;
    int b  = bh >> 4;
    const float* x = h + ((size_t)(b * SS + s) * EE + hh * DKK);
    float4 xa = *(const float4*)x;
    float4 xb = *(const float4*)(x + 4);
    float c[8];
    c[0] = cosf(xa.x + theta[0]); c[1] = cosf(xa.y + theta[1]);
    c[2] = cosf(xa.z + theta[2]); c[3] = cosf(xa.w + theta[3]);
    c[4] = cosf(xb.x + theta[4]); c[5] = cosf(xb.y + theta[5]);
    c[6] = cosf(xb.z + theta[6]); c[7] = cosf(xb.w + theta[7]);
    float outv[8];
    outv[0] = c[1] * c[2] * c[3] * c[4] * c[5] * c[6] * c[7];   // z0
    float cum = c[0];
#pragma unroll
    for (int d = 1; d < 8; d++) { cum *= c[d]; outv[d] = cum; }
    float4* dst = (float4*)(enc + (size_t)i * 8);
    dst[0] = make_float4(outv[0], outv[1], outv[2], outv[3]);
    dst[1] = make_float4(outv[4], outv[5], outv[6], outv[7]);
}

// ---------------------------------------------------------------------------
// Per (b,h): scores = enc@enc^T/sqrt(8), softmax, o = attn@enc.
// |score*log2e| <= 4.08 (|enc|<=1) so no max-subtraction pass is needed:
// single-pass exp2 accumulate is exact softmax (shift-invariant).
// Block = 256 threads = 256 query rows; 2 blocks per (b,h).
// ---------------------------------------------------------------------------
__global__ __launch_bounds__(256) void attn_kernel(
    const float* __restrict__ enc, float* __restrict__ o)
{
    __shared__ __align__(16) float encL[SS * 8];
    int bh   = blockIdx.x >> 1;
    int half = blockIdx.x & 1;
    const float4* encG = (const float4*)(enc + (size_t)bh * SS * 8);
    float4* encLv = (float4*)encL;
    for (int i = threadIdx.x; i < SS * 2; i += 256) encLv[i] = encG[i];
    __syncthreads();

    int s = half * 256 + threadIdx.x;
    const float SC = 0.35355339059327373f * 1.4426950408889634f; // 1/sqrt(8)*log2(e)
    float q[8];
#pragma unroll
    for (int d = 0; d < 8; d++) q[d] = encL[s * 8 + d] * SC;

    float sum = 0.f;
    float a0 = 0, a1 = 0, a2 = 0, a3 = 0, a4 = 0, a5 = 0, a6 = 0, a7 = 0;
    for (int t = 0; t < SS; t++) {
        float4 ka = encLv[2 * t];
        float4 kb = encLv[2 * t + 1];
        float dot = q[0] * ka.x + q[1] * ka.y + q[2] * ka.z + q[3] * ka.w
                  + q[4] * kb.x + q[5] * kb.y + q[6] * kb.z + q[7] * kb.w;
        float w = exp2f(dot);
        sum += w;
        a0 += w * ka.x; a1 += w * ka.y; a2 += w * ka.z; a3 += w * ka.w;
        a4 += w * kb.x; a5 += w * kb.y; a6 += w * kb.z; a7 += w * kb.w;
    }
    float inv = 1.0f / sum;
    int b = bh >> 4, hh = bh & 15;
    float* dst = o + ((size_t)(b * SS + s) * EE + hh * 8);
    ((float4*)dst)[0] = make_float4(a0 * inv, a1 * inv, a2 * inv, a3 * inv);
    ((float4*)dst)[1] = make_float4(a4 * inv, a5 * inv, a6 * inv, a7 * inv);
}

// ---------------------------------------------------------------------------
// Per 16 tokens: h = LN1(h + o@Wo^T); FFN; h = LN2(h + f). 256 threads:
// tid -> (e = tid&127, g = tid>>7), each thread owns 8 tokens for its e.
// ---------------------------------------------------------------------------
__global__ __launch_bounds__(256) void fused_kernel(
    float* __restrict__ h, const float* __restrict__ o,
    const float* __restrict__ WoP, const float* __restrict__ W2P,
    const float* __restrict__ W1, const float* __restrict__ ffn_theta,
    const float* __restrict__ ln1g, const float* __restrict__ ln1b,
    const float* __restrict__ ln2g, const float* __restrict__ ln2b)
{
    __shared__ __align__(16) float oL[16 * 128];
    __shared__ __align__(16) float hL[16 * 128];
    __shared__ __align__(16) float measL[16 * 4];
    __shared__ __align__(16) float hidL[16 * 512];
    __shared__ float meanL[16], rstdL[16];

    int tid = threadIdx.x;
    int t0  = blockIdx.x * 16;

    const float4* oG = (const float4*)(o + (size_t)t0 * EE);
    const float4* hG = (const float4*)(h + (size_t)t0 * EE);
    float4* oLv = (float4*)oL;
    float4* hLv = (float4*)hL;
    for (int i = tid; i < 16 * 128 / 4; i += 256) { oLv[i] = oG[i]; hLv[i] = hG[i]; }
    __syncthreads();

    int e = tid & 127, g = tid >> 7;
    float ge1 = ln1g[e], be1 = ln1b[e], ge2 = ln2g[e], be2 = ln2b[e];

    // ---- v = h + o @ Wo^T ----
    float v[8];
#pragma unroll
    for (int t = 0; t < 8; t++) v[t] = hL[(g * 8 + t) * 128 + e];
    const float4* WoPv = (const float4*)WoP;
    for (int kq = 0; kq < 32; kq++) {
        float4 w = WoPv[kq * 128 + e];
#pragma unroll
        for (int t = 0; t < 8; t++) {
            const float4 ov = *(const float4*)&oL[(g * 8 + t) * 128 + kq * 4];
            v[t] += ov.x * w.x + ov.y * w.y + ov.z * w.z + ov.w * w.w;
        }
    }
    // write for LN1 reduction (each thread rewrites only elements it owns)
#pragma unroll
    for (int t = 0; t < 8; t++) hL[(g * 8 + t) * 128 + e] = v[t];
    __syncthreads();

    // ---- LN1: 16 lanes per token ----
    int tt = tid >> 4, l16 = tid & 15;
    {
        float sm = 0.f, sq = 0.f;
#pragma unroll
        for (int i = 0; i < 8; i++) {
            float x = hL[tt * 128 + l16 + 16 * i];
            sm += x; sq += x * x;
        }
#pragma unroll
        for (int ofs = 8; ofs >= 1; ofs >>= 1) {
            sm += __shfl_xor(sm, ofs);
            sq += __shfl_xor(sq, ofs);
        }
        if (l16 == 0) {
            float mu = sm * (1.f / 128.f);
            meanL[tt] = mu;
            rstdL[tt] = rsqrtf(sq * (1.f / 128.f) - mu * mu + 1e-5f);
        }
    }
    __syncthreads();
    float h1[8];
#pragma unroll
    for (int t = 0; t < 8; t++) {
        int idx = g * 8 + t;
        h1[t] = (v[t] - meanL[idx]) * rstdL[idx] * ge1 + be1;
        hL[idx * 128 + e] = h1[t];
    }
    __syncthreads();

    // ---- meas = cos(h1[:, :4]) * cos(theta) ----
    if (tid < 64) {
        int t = tid >> 2, k = tid & 3;
        measL[tid] = cosf(hL[t * 128 + k]) * cosf(ffn_theta[k]);
    }
    __syncthreads();

    // ---- hidden = relu(meas @ W1^T), 512 units x 16 tokens ----
#pragma unroll
    for (int jj = 0; jj < 2; jj++) {
        int j = tid + jj * 256;
        float4 w1v = *(const float4*)&W1[j * 4];
        for (int t = 0; t < 16; t++) {
            float4 mv = *(const float4*)&measL[t * 4];
            float hv = mv.x * w1v.x + mv.y * w1v.y + mv.z * w1v.z + mv.w * w1v.w;
            hidL[t * 512 + j] = fmaxf(hv, 0.f);
        }
    }
    __syncthreads();

    // ---- f = hidden @ W2^T ----
    float f[8];
#pragma unroll
    for (int t = 0; t < 8; t++) f[t] = 0.f;
    const float4* W2Pv = (const float4*)W2P;
    for (int jq = 0; jq < 128; jq++) {
        float4 w = W2Pv[jq * 128 + e];
#pragma unroll
        for (int t = 0; t < 8; t++) {
            const float4 hv = *(const float4*)&hidL[(g * 8 + t) * 512 + jq * 4];
            f[t] += hv.x * w.x + hv.y * w.y + hv.z * w.z + hv.w * w.w;
        }
    }

    // ---- v2 = h1 + f, LN2, write h ----
#pragma unroll
    for (int t = 0; t < 8; t++) { v[t] = h1[t] + f[t]; hL[(g * 8 + t) * 128 + e] = v[t]; }
    __syncthreads();
    {
        float sm = 0.f, sq = 0.f;
#pragma unroll
        for (int i = 0; i < 8; i++) {
            float x = hL[tt * 128 + l16 + 16 * i];
            sm += x; sq += x * x;
        }
#pragma unroll
        for (int ofs = 8; ofs >= 1; ofs >>= 1) {
            sm += __shfl_xor(sm, ofs);
            sq += __shfl_xor(sq, ofs);
        }
        if (l16 == 0) {
            float mu = sm * (1.f / 128.f);
            meanL[tt] = mu;
            rstdL[tt] = rsqrtf(sq * (1.f / 128.f) - mu * mu + 1e-5f);
        }
    }
    __syncthreads();
#pragma unroll
    for (int t = 0; t < 8; t++) {
        int idx = g * 8 + t;
        float hv = (v[t] - meanL[idx]) * rstdL[idx] * ge2 + be2;
        h[(size_t)(t0 + idx) * 128 + e] = hv;
    }
}

// ---------------------------------------------------------------------------
// pooled = mean_s h; out = pooled @ Wc^T + bc
// ---------------------------------------------------------------------------
__global__ __launch_bounds__(128) void head_kernel(
    const float* __restrict__ h, const float* __restrict__ Wc,
    const float* __restrict__ bc, float* __restrict__ out)
{
    __shared__ float pooled[EE];
    int b = blockIdx.x;
    int e = threadIdx.x;
    float sm = 0.f;
    for (int s = 0; s < SS; s++) sm += h[((size_t)b * SS + s) * EE + e];
    pooled[e] = sm * (1.f / (float)SS);
    __syncthreads();
    if (e < CC) {
        float acc = bc[e];
        for (int k = 0; k < EE; k++) acc += pooled[k] * Wc[e * EE + k];
        out[b * CC + e] = acc;
    }
}

// ---------------------------------------------------------------------------
extern "C" void kernel_launch(void* const* d_in, const int* in_sizes, int n_in,
                              void* d_out, int out_size, void* d_ws, size_t ws_size,
                              hipStream_t stream)
{
    const int*   tokens     = (const int*)d_in[0];
    const float* emb        = (const float*)d_in[1];
    const float* attn_theta = (const float*)d_in[2];
    const float* ffn_theta  = (const float*)d_in[3];
    const float* Wo         = (const float*)d_in[4];
    const float* W1         = (const float*)d_in[5];
    const float* W2         = (const float*)d_in[6];
    const float* ln1g       = (const float*)d_in[7];
    const float* ln1b       = (const float*)d_in[8];
    const float* ln2g       = (const float*)d_in[9];
    const float* ln2b       = (const float*)d_in[10];
    const float* Wc         = (const float*)d_in[11];
    const float* bc         = (const float*)d_in[12];
    float* out = (float*)d_out;

    float* ws  = (float*)d_ws;
    float* h   = ws;                  // 524288 floats
    float* enc = ws + 524288;         // 524288
    float* o   = ws + 1048576;        // 524288
    float* WoP = ws + 1572864;        // 65536
    float* W2P = ws + 1638400;        // 262144

    transpose_kernel<<<dim3(1024), dim3(256), 0, stream>>>(Wo, W2, WoP, W2P);
    embed_kernel<<<dim3(2048), dim3(256), 0, stream>>>(tokens, emb, h);

    for (int l = 0; l < LL; l++) {
        enc_kernel<<<dim3(256), dim3(256), 0, stream>>>(h, attn_theta + l * DKK, enc);
        attn_kernel<<<dim3(256), dim3(256), 0, stream>>>(enc, o);
        fused_kernel<<<dim3(256), dim3(256), 0, stream>>>(
            h, o,
            WoP + (size_t)l * EE * EE,
            W2P + (size_t)l * FF * EE,
            W1 + (size_t)l * FF * NQQ,
            ffn_theta + (size_t)l * NQQ,
            ln1g + (size_t)l * EE, ln1b + (size_t)l * EE,
            ln2g + (size_t)l * EE, ln2b + (size_t)l * EE);
    }

    head_kernel<<<dim3(BB), dim3(128), 0, stream>>>(h, Wc, bc, out);
}